// Round 1
// 18086.690 us; speedup vs baseline: 2.0940x; 2.0940x over previous
//
#include <hip/hip_runtime.h>

#define NHIDC 1024
#define BSZ   128
#define TLEN  256
#define SLOT  (BSZ*NHIDC)   // 131072 elements per state slot

using bf16x8 = __attribute__((ext_vector_type(8))) short;
using f32x4  = __attribute__((ext_vector_type(4))) float;

__device__ inline short f2bf(float f){
  union {float f; unsigned u;} v; v.f = f;
  unsigned u = v.u;
  unsigned r = u + 0x7fffu + ((u >> 16) & 1u);
  return (short)(r >> 16);
}

__device__ inline float bact(int act, float x){
  switch(act){
    case 0: return tanhf(x);
    case 1: return 1.f/(1.f+__expf(-x));
    case 2: return x > 0.f ? x : 0.f;
    default: return x;
  }
}

// Transpose-convert: D[n][k] (bf16) = S[k][n] (f32), S is K x 2048, per blockIdx.z matrix.
__global__ __launch_bounds__(256) void transpose_bf16(const float* __restrict__ src,
                                                      short* __restrict__ dst, int K){
  const size_t mat = blockIdx.z;
  const float* S = src + mat * (size_t)K * 2048;
  short* D = dst + mat * (size_t)K * 2048;
  __shared__ float tile[32][33];
  int n0 = blockIdx.x * 32;
  int k0 = blockIdx.y * 32;
  int tx = threadIdx.x & 31, ty = threadIdx.x >> 5;
  #pragma unroll
  for (int i=0;i<4;i++){
    tile[ty + i*8][tx] = S[(size_t)(k0 + ty + i*8)*2048 + n0 + tx];
  }
  __syncthreads();
  #pragma unroll
  for (int i=0;i<4;i++){
    int n = n0 + ty + i*8;
    D[(size_t)n*K + k0 + tx] = f2bf(tile[tx][ty + i*8]);
  }
}

// fp32 -> bf16 bulk convert (for initial h)
__global__ __launch_bounds__(256) void f32_to_bf16(const float* __restrict__ src,
                                                   short* __restrict__ dst){
  int i = (blockIdx.x*256 + threadIdx.x)*4;
  float4 v = *(const float4*)(src + i);
  short4 o;
  o.x = f2bf(v.x); o.y = f2bf(v.y); o.z = f2bf(v.z); o.w = f2bf(v.w);
  *(short4*)(dst + i) = o;
}

// Gated matmul stage, K-split 4-way across waves + LDS reduce.
// Each block: one 16-row x 16-paired-col output tile. grid.x = 512 (8 rowtiles x 64 colpairs).
//   ch = A @ W   (A: 128 x K bf16 (precomputed), W: bf16 [2048][K] row-major, transposed)
//   sout = sprev + sigmoid(ch[:, :1024]) * (act(ch[:, 1024:]) - sprev)
// g = (weight_index, sprev_slot, sout_slot, act)
// STAGE0: A = [x_t | h]  (K=2048); waves 0,1 take x half (fp32, convert), waves 2,3 take h bf16.
template<int K, bool STAGE0>
__global__ __launch_bounds__(256) void stage_kernel(
    float* __restrict__ states, short* __restrict__ sbf,
    const short* __restrict__ Wbase,
    const float* __restrict__ x, int t,
    int4 ga, int4 gb, int4 gc)
{
  int4 g = (blockIdx.y==0) ? ga : (blockIdx.y==1 ? gb : gc);
  const short* W = Wbase + (size_t)g.x * (size_t)2048 * (size_t)K;
  const float* sprev = states + (size_t)g.y * SLOT;
  const short* sprevb = sbf + (size_t)g.y * SLOT;
  float* sout = states + (size_t)g.z * SLOT;
  short* soutb = sbf + (size_t)g.z * SLOT;
  const int act = g.w;

  const int lane = threadIdx.x & 63;
  const int wave = threadIdx.x >> 6;
  const int m = lane & 15;
  const int q = lane >> 4;

  const int rowbase = (blockIdx.x >> 6) * 16;   // 8 row tiles
  const int col0 = (blockIdx.x & 63) * 16;      // 64 paired-column tiles (j and j+1024)
  const short* wC = W + (size_t)(col0 + m) * K;
  const short* wH = W + (size_t)(col0 + m + 1024) * K;

  constexpr int KW = K >> 2;                    // per-wave K range
  const int kw0 = wave * KW;
  const int arow = rowbase + m;

  f32x4 accC = {0.f,0.f,0.f,0.f};
  f32x4 accH = {0.f,0.f,0.f,0.f};

  if (STAGE0) {
    if (wave < 2) {
      // x half: fp32 load + convert (x is read once per element per stage; no bf16 cache)
      const float* xp = x + ((size_t)arow*TLEN + t)*NHIDC;
      #pragma unroll
      for (int k0 = 0; k0 < KW; k0 += 32) {
        int k = kw0 + k0 + q*8;
        float4 ua = *(const float4*)(xp + k);
        float4 ub = *(const float4*)(xp + k + 4);
        bf16x8 a;
        a[0]=f2bf(ua.x); a[1]=f2bf(ua.y); a[2]=f2bf(ua.z); a[3]=f2bf(ua.w);
        a[4]=f2bf(ub.x); a[5]=f2bf(ub.y); a[6]=f2bf(ub.z); a[7]=f2bf(ub.w);
        bf16x8 bC = *(const bf16x8*)(wC + k);
        bf16x8 bH = *(const bf16x8*)(wH + k);
        accC = __builtin_amdgcn_mfma_f32_16x16x32_bf16(a, bC, accC, 0, 0, 0);
        accH = __builtin_amdgcn_mfma_f32_16x16x32_bf16(a, bH, accH, 0, 0, 0);
      }
    } else {
      // h half: bf16 precomputed (slot 9 == g.y)
      const short* ap = sprevb + (size_t)arow*NHIDC - 1024;
      #pragma unroll
      for (int k0 = 0; k0 < KW; k0 += 32) {
        int k = kw0 + k0 + q*8;
        bf16x8 a  = *(const bf16x8*)(ap + k);
        bf16x8 bC = *(const bf16x8*)(wC + k);
        bf16x8 bH = *(const bf16x8*)(wH + k);
        accC = __builtin_amdgcn_mfma_f32_16x16x32_bf16(a, bC, accC, 0, 0, 0);
        accH = __builtin_amdgcn_mfma_f32_16x16x32_bf16(a, bH, accH, 0, 0, 0);
      }
    }
  } else {
    const short* ap = sprevb + (size_t)arow*NHIDC;
    #pragma unroll
    for (int k0 = 0; k0 < KW; k0 += 32) {
      int k = kw0 + k0 + q*8;
      bf16x8 a  = *(const bf16x8*)(ap + k);
      bf16x8 bC = *(const bf16x8*)(wC + k);
      bf16x8 bH = *(const bf16x8*)(wH + k);
      accC = __builtin_amdgcn_mfma_f32_16x16x32_bf16(a, bC, accC, 0, 0, 0);
      accH = __builtin_amdgcn_mfma_f32_16x16x32_bf16(a, bH, accH, 0, 0, 0);
    }
  }

  // Cross-wave K reduction through LDS (pad 9 -> stride 9 words, conflict-free).
  __shared__ float red[4][64][9];
  #pragma unroll
  for (int i=0;i<4;i++){
    red[wave][lane][i]   = accC[i];
    red[wave][lane][4+i] = accH[i];
  }
  __syncthreads();

  // wave w finalizes accumulator index i == w  (row = rowbase + q*4 + i)
  float cv = red[0][lane][wave]   + red[1][lane][wave]
           + red[2][lane][wave]   + red[3][lane][wave];
  float hv = red[0][lane][4+wave] + red[1][lane][4+wave]
           + red[2][lane][4+wave] + red[3][lane][4+wave];
  int b = rowbase + q*4 + wave;
  size_t off = (size_t)b*NHIDC + col0 + m;
  float sp = sprev[off];
  float cg = 1.f/(1.f+__expf(-cv));
  float hh = bact(act, hv);
  float so = sp + cg*(hh - sp);
  sout[off] = so;
  soutb[off] = f2bf(so);
}

// mean of slots 1..8 -> h (slot 9, fp32 + bf16), output slab, and tail copy at t==T-1
__global__ __launch_bounds__(256) void mean_kernel(float* __restrict__ states,
                                                   short* __restrict__ sbf,
                                                   float* __restrict__ out, int t){
  int idx = (blockIdx.x*256 + threadIdx.x)*4;   // 0..131068, step 4
  float4 s = {0.f,0.f,0.f,0.f};
  #pragma unroll
  for (int i=1;i<=8;i++){
    float4 v = *(const float4*)(states + (size_t)i*SLOT + idx);
    s.x += v.x; s.y += v.y; s.z += v.z; s.w += v.w;
  }
  s.x *= 0.125f; s.y *= 0.125f; s.z *= 0.125f; s.w *= 0.125f;
  *(float4*)(states + (size_t)9*SLOT + idx) = s;
  short4 o;
  o.x = f2bf(s.x); o.y = f2bf(s.y); o.z = f2bf(s.z); o.w = f2bf(s.w);
  *(short4*)(sbf + (size_t)9*SLOT + idx) = o;
  int b = idx >> 10, j = idx & 1023;
  *(float4*)(out + ((size_t)b*TLEN + t)*NHIDC + j) = s;
  if (t == TLEN-1){
    *(float4*)(out + (size_t)BSZ*TLEN*NHIDC + idx) = s;
  }
}

extern "C" void kernel_launch(void* const* d_in, const int* in_sizes, int n_in,
                              void* d_out, int out_size, void* d_ws, size_t ws_size,
                              hipStream_t stream) {
  const float* x  = (const float*)d_in[0];   // (128, 256, 1024)
  const float* h0 = (const float*)d_in[1];   // (1, 128, 1024)
  const float* W0 = (const float*)d_in[2];   // (2048, 2048)
  const float* Ws = (const float*)d_in[3];   // (8, 1024, 2048)
  float* out = (float*)d_out;

  // ws layout: [0) W0T bf16 8MB | [8MB) WsT bf16 32MB | [40MB) states fp32 10 slots (5MB)
  //            [45MB) states bf16 10 slots (2.5MB)
  char* wsb = (char*)d_ws;
  short* W0T = (short*)wsb;
  short* WsT = (short*)(wsb + (size_t)8*1024*1024);
  float* states = (float*)(wsb + (size_t)40*1024*1024);
  short* sbf = (short*)(wsb + (size_t)45*1024*1024);

  transpose_bf16<<<dim3(64,64,1),256,0,stream>>>(W0, W0T, 2048);
  transpose_bf16<<<dim3(64,32,8),256,0,stream>>>(Ws, WsT, 1024);

  hipMemcpyAsync(states + (size_t)9*SLOT, h0, (size_t)SLOT*sizeof(float),
                 hipMemcpyDeviceToDevice, stream);
  f32_to_bf16<<<dim3(128,1),256,0,stream>>>(h0, sbf + (size_t)9*SLOT);

  const int4 gz = make_int4(0,0,0,0);
  for (int t=0; t<TLEN; t++){
    // stage0: ch=[x|h]@W0 ; s0 = h + sig(cC)*(tanh(cH)-h)   (slot9 -> slot0)
    stage_kernel<2048,true><<<dim3(512,1),256,0,stream>>>(states, sbf, W0T, x, t,
        make_int4(0,9,0,0), gz, gz);
    // g0: sigmoid, s0 -> s1
    stage_kernel<1024,false><<<dim3(512,1),256,0,stream>>>(states, sbf, WsT, nullptr, 0,
        make_int4(0,0,1,1), gz, gz);
    // g1: relu s1->s2 ; g2: relu s1->s3 ; g3: identity s1->s4
    stage_kernel<1024,false><<<dim3(512,3),256,0,stream>>>(states, sbf, WsT, nullptr, 0,
        make_int4(1,1,2,2), make_int4(2,1,3,2), make_int4(3,1,4,3));
    // g4: tanh s2->s5 ; g6: tanh s3->s7
    stage_kernel<1024,false><<<dim3(512,2),256,0,stream>>>(states, sbf, WsT, nullptr, 0,
        make_int4(4,2,5,0), make_int4(6,3,7,0), gz);
    // g5: sigmoid s5->s6 ; g7: relu s5->s8
    stage_kernel<1024,false><<<dim3(512,2),256,0,stream>>>(states, sbf, WsT, nullptr, 0,
        make_int4(5,5,6,1), make_int4(7,5,8,2), gz);
    // mean(s1..s8) -> h (fp32+bf16), out[:,t,:], tail at t==255
    mean_kernel<<<dim3(128,1,1),256,0,stream>>>(states, sbf, out, t);
  }
}